// Round 11
// baseline (332.340 us; speedup 1.0000x reference)
//
#include <hip/hip_runtime.h>
#include <hip/hip_bf16.h>
#include <math.h>

#define B_ 32
#define S_ 128
#define L_ 1024
#define D_ 1024

typedef unsigned short u16;
typedef __attribute__((ext_vector_type(8))) __bf16 bf16x8;
typedef __attribute__((ext_vector_type(8))) short short8;
typedef __attribute__((ext_vector_type(4))) float f32x4;

__device__ __forceinline__ float bf2f(u16 u) {
    return __uint_as_float(((unsigned)u) << 16);
}
__device__ __forceinline__ u16 f2bf(float f) {
    unsigned u = __float_as_uint(f);
    u += 0x7FFF + ((u >> 16) & 1);
    return (u16)(u >> 16);
}
__device__ __forceinline__ float gelu_tanh(float x) {
    float x3 = x * x * x;
    float t = tanhf(0.7978845608028654f * (x + 0.044715f * x3));
    return 0.5f * x * (1.0f + t);
}
__device__ __forceinline__ float sigmoidf(float x) {
    return 1.0f / (1.0f + expf(-x));
}
__device__ __forceinline__ void gld16(const void* g, void* l) {
    __builtin_amdgcn_global_load_lds((const __attribute__((address_space(1))) void*)g,
                                     (__attribute__((address_space(3))) void*)l, 16, 0, 0);
}

// ---------------- K0: S4D SSM kernel ---------------------------------------
__global__ __launch_bounds__(256) void k_ssmk(
        const float* __restrict__ log_dt, const float* __restrict__ Alr,
        const float* __restrict__ Aim, const float* __restrict__ Cr,
        const float* __restrict__ Ci, float* __restrict__ Kt) {
    int tid = blockIdx.x * 256 + threadIdx.x;
    int d = tid & (D_ - 1);
    int j = tid >> 10;
    float dt = expf(log_dt[d]);
    float acc = 0.f;
    #pragma unroll
    for (int n = 0; n < 4; ++n) {
        float ar = -expf(Alr[d * 4 + n]);
        float ai = Aim[d * 4 + n];
        float wr = ar * dt, wi = ai * dt;
        float ew = expf(wr);
        float sw, cw; sincosf(wi, &sw, &cw);
        float ur = ew * cw - 1.0f, ui = ew * sw;
        float inv = 1.0f / (ar * ar + ai * ai);
        float bdr = (ur * ar + ui * ai) * inv;
        float bdi = (ui * ar - ur * ai) * inv;
        float cr = Cr[d * 4 + n], ci = Ci[d * 4 + n];
        float cbr = cr * bdr - ci * bdi;
        float cbi = cr * bdi + ci * bdr;
        float ej = expf(wr * (float)j);
        float sj, cj; sincosf(wi * (float)j, &sj, &cj);
        acc += 2.0f * ej * (cbr * cj - cbi * sj);
    }
    Kt[j * D_ + d] = acc;
}

// ---------------- c1[s]=sum gam_k Wd[k,s]; c2[s]=sum bet_k Wd[k,s]+bd[s] ---
__global__ __launch_bounds__(256) void k_c12(
        const float* __restrict__ Wd, const float* __restrict__ gam,
        const float* __restrict__ bet, const float* __restrict__ bd,
        float* __restrict__ c12) {
    int s = blockIdx.x;
    int t = threadIdx.x;
    float a1 = 0.f, a2 = 0.f;
    #pragma unroll
    for (int it = 0; it < 4; ++it) {
        int k = it * 256 + t;
        float w = Wd[(size_t)k * 128 + s];
        a1 += gam[k] * w;
        a2 += bet[k] * w;
    }
    #pragma unroll
    for (int off = 32; off > 0; off >>= 1) {
        a1 += __shfl_down(a1, off);
        a2 += __shfl_down(a2, off);
    }
    __shared__ float r1[4], r2[4];
    int wid = t >> 6, lane = t & 63;
    if (lane == 0) { r1[wid] = a1; r2[wid] = a2; }
    __syncthreads();
    if (t == 0) {
        c12[s] = r1[0] + r1[1] + r1[2] + r1[3];
        c12[128 + s] = r2[0] + r2[1] + r2[2] + r2[3] + bd[s];
    }
}

// ---------------- transpose+cast (+optional row scale): f32[R][C]->bf16[C][R]
__global__ __launch_bounds__(256) void k_tcast(
        const float* __restrict__ src0, u16* __restrict__ dst0, int R, int C,
        const float* __restrict__ rowscale) {
    __shared__ float tile[64][65];
    const float* src = src0 + (size_t)blockIdx.z * R * C;
    u16* dst = dst0 + (size_t)blockIdx.z * R * C;
    int c0 = blockIdx.x * 64;
    int r0 = blockIdx.y * 64;
    int t = threadIdx.x;
    #pragma unroll
    for (int p = 0; p < 4; ++p) {
        int fid = p * 256 + t;
        int rr = fid >> 4, cc = (fid & 15) * 4;
        float4 v = *(const float4*)&src[(size_t)(r0 + rr) * C + c0 + cc];
        float sc = rowscale ? rowscale[r0 + rr] : 1.0f;
        tile[rr][cc + 0] = v.x * sc; tile[rr][cc + 1] = v.y * sc;
        tile[rr][cc + 2] = v.z * sc; tile[rr][cc + 3] = v.w * sc;
    }
    __syncthreads();
    #pragma unroll
    for (int p = 0; p < 4; ++p) {
        int fid = p * 256 + t;
        int rr = fid >> 4, cc = (fid & 15) * 4;
        ushort4 o;
        o.x = f2bf(tile[cc + 0][rr]);
        o.y = f2bf(tile[cc + 1][rr]);
        o.z = f2bf(tile[cc + 2][rr]);
        o.w = f2bf(tile[cc + 3][rr]);
        *(ushort4*)&dst[(size_t)(c0 + rr) * R + r0 + cc] = o;
    }
}

// ---------------- K1: encoder MFMA ------------------------------------------
__global__ __launch_bounds__(256) void k_enc_mfma(
        const u16* __restrict__ xb, const u16* __restrict__ WeT,
        const float* __restrict__ be, u16* __restrict__ hb) {
    __shared__ u16 As[128 * 128];
    __shared__ u16 Bs[128 * 128];
    int t = threadIdx.x;
    int lane = t & 63, wid = t >> 6;
    int wr = wid & 1, wc = wid >> 1;
    int orig = blockIdx.x;
    int wgid = (orig & 7) * 256 + (orig >> 3);
    int m0 = (wgid >> 3) * 128;
    int e0 = (wgid & 7) * 128;

    #pragma unroll
    for (int c = 0; c < 8; ++c) {
        int ch = wid * 8 + c;
        int r = ch * 4 + (lane >> 4);
        int g = (lane & 15) ^ (r & 15);
        gld16(&xb[(size_t)(m0 + r) * 128 + g * 8], &As[ch * 512]);
        gld16(&WeT[(size_t)(e0 + r) * 128 + g * 8], &Bs[ch * 512]);
    }
    int co4[4];
    #pragma unroll
    for (int kh = 0; kh < 4; ++kh)
        co4[kh] = ((((lane >> 4) + kh * 4) ^ (lane & 15)) * 8);
    int arow[4], brow[4];
    #pragma unroll
    for (int i = 0; i < 4; ++i) arow[i] = (wr * 64 + i * 16 + (lane & 15)) * 128;
    #pragma unroll
    for (int q = 0; q < 4; ++q) brow[q] = (wc * 64 + q * 16 + (lane & 15)) * 128;

    __syncthreads();
    f32x4 acc[4][4] = {};
    #pragma unroll
    for (int kh = 0; kh < 4; ++kh) {
        bf16x8 af[4], bfr[4];
        #pragma unroll
        for (int i = 0; i < 4; ++i) af[i] = *(const bf16x8*)&As[arow[i] + co4[kh]];
        #pragma unroll
        for (int q = 0; q < 4; ++q) bfr[q] = *(const bf16x8*)&Bs[brow[q] + co4[kh]];
        __builtin_amdgcn_s_setprio(1);
        #pragma unroll
        for (int i = 0; i < 4; ++i)
            #pragma unroll
            for (int q = 0; q < 4; ++q)
                acc[i][q] = __builtin_amdgcn_mfma_f32_16x16x32_bf16(af[i], bfr[q], acc[i][q], 0, 0, 0);
        __builtin_amdgcn_s_setprio(0);
    }
    #pragma unroll
    for (int q = 0; q < 4; ++q) {
        int e = e0 + wc * 64 + q * 16 + (lane & 15);
        float bias = be[e];
        #pragma unroll
        for (int i = 0; i < 4; ++i) {
            #pragma unroll
            for (int r = 0; r < 4; ++r) {
                int m = m0 + wr * 64 + i * 16 + (lane >> 4) * 4 + r;
                hb[(size_t)m * 1024 + e] = f2bf(acc[i][q][r] + bias);
            }
        }
    }
}

// ---------------- K2: conv, halo-free ring sweep ---------------------------
__global__ __launch_bounds__(256) void k_conv(
        const u16* __restrict__ hb, const float* __restrict__ Kt,
        const float* __restrict__ Dv, u16* __restrict__ yg) {
    __shared__ float hs[128][68];
    int b = blockIdx.y;
    int d0 = blockIdx.x * 64;
    int t = threadIdx.x;
    int dl = t & 63, lg = t >> 6;
    {
        int r = 64 + (t >> 2), cg0 = (t & 3) * 16;
        #pragma unroll
        for (int j = 0; j < 4; ++j)
            *(float4*)&hs[r][cg0 + j * 4] = make_float4(0.f, 0.f, 0.f, 0.f);
    }
    float kr[64];
    #pragma unroll
    for (int j = 0; j < 64; ++j) kr[j] = Kt[j * 1024 + d0 + dl];
    float Dd = Dv[d0 + dl];
    int lr = t >> 2, cg = (t & 3) * 16;
    for (int it = 0; it < 16; ++it) {
        int l0 = it * 64;
        {
            int l = l0 + lr;
            int row = l & 127;
            const u16* src = &hb[((size_t)b * 1024 + l) * 1024 + d0 + cg];
            #pragma unroll
            for (int h = 0; h < 2; ++h) {
                ushort4 u0 = *(const ushort4*)&src[h * 8];
                ushort4 u1 = *(const ushort4*)&src[h * 8 + 4];
                *(float4*)&hs[row][cg + h * 8] =
                    make_float4(bf2f(u0.x), bf2f(u0.y), bf2f(u0.z), bf2f(u0.w));
                *(float4*)&hs[row][cg + h * 8 + 4] =
                    make_float4(bf2f(u1.x), bf2f(u1.y), bf2f(u1.z), bf2f(u1.w));
            }
        }
        __syncthreads();
        float acc[16] = {};
        int rb = l0 + 65 + lg * 16;
        #pragma unroll
        for (int s = 0; s < 15; ++s) {
            float hv = hs[(rb + s) & 127][dl];
            #pragma unroll
            for (int i = 0; i <= 14; ++i)
                if (i <= s) acc[i] = fmaf(kr[i + 63 - s], hv, acc[i]);
        }
        #pragma unroll
        for (int s = 15; s < 64; ++s) {
            float hv = hs[(rb + s) & 127][dl];
            #pragma unroll
            for (int i = 0; i < 16; ++i)
                acc[i] = fmaf(kr[i + 63 - s], hv, acc[i]);
        }
        #pragma unroll
        for (int s = 64; s < 79; ++s) {
            float hv = hs[(rb + s) & 127][dl];
            #pragma unroll
            for (int i = 1; i < 16; ++i)
                if (i >= s - 63) acc[i] = fmaf(kr[i + 63 - s], hv, acc[i]);
        }
        #pragma unroll
        for (int i = 0; i < 16; ++i) {
            int l = l0 + lg * 16 + i;
            float z = hs[l & 127][dl];
            float y = acc[i] + Dd * z;
            yg[((size_t)b * 1024 + l) * 1024 + d0 + dl] = f2bf(gelu_tanh(y));
        }
        __syncthreads();
    }
}

// ---------------- K3: GLU GEMM 256x256, 2-barrier overlapped tile ----------
// Same regions/stage-ledger/swizzles/epilogue as r8/r10 (proven). Change:
// intra-tile barriers cut 4 -> 2 so waves de-sync and ds_read drain overlaps
// MFMA. Mid-barrier placed after all cbuf A0/B0 fragment reads are consumed
// (their MFMAs force lgkm completion), making the t+2 stages into cbuf safe.
__global__ __launch_bounds__(512, 2) void k_glu256(
        const u16* __restrict__ yg, const u16* __restrict__ WgT,
        const float* __restrict__ bg, u16* __restrict__ hb) {
    __shared__ u16 S[65536];   // A: [buf*2+h]*8192, B: 32768 + [buf*2+h]*8192
    int t = threadIdx.x;
    int lane = t & 63, wid = t >> 6;
    int wr = wid >> 2, wc = wid & 3;

    int orig = blockIdx.x;
    int wgid = (orig & 7) * 128 + (orig >> 3);   // bijective (1024 % 8 == 0)
    int m0 = (wgid >> 3) * 256;
    int p0g = (wgid & 7) * 128;

    int gofs = (((lane & 7) ^ ((lane >> 3) & 7)) * 8);
    int ch0 = wid * 2, ch1 = ch0 + 1;
    int dst0 = ch0 * 512 + lane * 8;
    int dst1 = ch1 * 512 + lane * 8;
    int gmA[2][2], gmB[2][2];
    #pragma unroll
    for (int h = 0; h < 2; ++h) {
        #pragma unroll
        for (int j = 0; j < 2; ++j) {
            int ch = ch0 + j;
            gmA[h][j] = m0 + (ch >> 3) * 128 + h * 64 + (ch & 7) * 8 + (lane >> 3);
            int r = (ch >> 2) * 64 + h * 32 + (ch & 3) * 8 + (lane >> 3);
            gmB[h][j] = ((r >> 4) & 1) * 1024 + p0g + (((r >> 5) << 4) | (r & 15));
        }
    }
    int co[2];
    co[0] = (((lane >> 4) + 0) ^ (lane & 7)) * 8;
    co[1] = (((lane >> 4) + 4) ^ (lane & 7)) * 8;
    int arow[4], brow[2];
    #pragma unroll
    for (int i = 0; i < 4; ++i) arow[i] = (wr * 64 + i * 16 + (lane & 15)) * 64;
    #pragma unroll
    for (int q = 0; q < 2; ++q) brow[q] = (wc * 32 + q * 16 + (lane & 15)) * 64;

#define GLD_A(H, BUF, K0) { u16* d_ = &S[((BUF) * 2 + (H)) * 8192]; \
    gld16(&yg[(size_t)gmA[H][0] * 1024 + (K0) + gofs], d_ + dst0); \
    gld16(&yg[(size_t)gmA[H][1] * 1024 + (K0) + gofs], d_ + dst1); }
#define GLD_B(H, BUF, K0) { u16* d_ = &S[32768 + ((BUF) * 2 + (H)) * 8192]; \
    gld16(&WgT[(size_t)gmB[H][0] * 1024 + (K0) + gofs], d_ + dst0); \
    gld16(&WgT[(size_t)gmB[H][1] * 1024 + (K0) + gofs], d_ + dst1); }

#define RD_AH(MS) { const u16* Ar_ = &S[(cbuf * 2 + (MS)) * 8192]; \
    _Pragma("unroll") for (int i = 0; i < 4; ++i) { \
        a_[i][0] = *(const bf16x8*)&Ar_[arow[i] + co[0]]; \
        a_[i][1] = *(const bf16x8*)&Ar_[arow[i] + co[1]]; } }
#define RD_BH(NS, BB) { const u16* Br_ = &S[32768 + (cbuf * 2 + (NS)) * 8192]; \
    _Pragma("unroll") for (int q = 0; q < 2; ++q) { \
        BB[q][0] = *(const bf16x8*)&Br_[brow[q] + co[0]]; \
        BB[q][1] = *(const bf16x8*)&Br_[brow[q] + co[1]]; } }
#define MFMA16(MS, NS, BB) { __builtin_amdgcn_s_setprio(1); \
    _Pragma("unroll") for (int i = 0; i < 4; ++i) \
        _Pragma("unroll") for (int q = 0; q < 2; ++q) { \
            acc[(MS) * 4 + i][(NS) * 2 + q] = __builtin_amdgcn_mfma_f32_16x16x32_bf16( \
                a_[i][0], BB[q][0], acc[(MS) * 4 + i][(NS) * 2 + q], 0, 0, 0); \
            acc[(MS) * 4 + i][(NS) * 2 + q] = __builtin_amdgcn_mfma_f32_16x16x32_bf16( \
                a_[i][1], BB[q][1], acc[(MS) * 4 + i][(NS) * 2 + q], 0, 0, 0); } \
    __builtin_amdgcn_s_setprio(0); }

    f32x4 acc[8][4] = {};
    bf16x8 a_[4][2], b0_[2][2], b1_[2][2];

    // prologue (ledger order): A0(0) B0(0) B1(0) A1(0) A0(1) B0(1)
    GLD_A(0, 0, 0); GLD_B(0, 0, 0); GLD_B(1, 0, 0); GLD_A(1, 0, 0);
    GLD_A(0, 1, 64); GLD_B(0, 1, 64);

    for (int kt = 0; kt < 15; ++kt) {
        int cbuf = kt & 1, nbuf = cbuf ^ 1;
        int k1 = (kt + 1) * 64, k2 = (kt + 2) * 64;
        asm volatile("s_waitcnt vmcnt(4)" ::: "memory");
        __builtin_amdgcn_s_barrier();
        __builtin_amdgcn_sched_barrier(0);
        // region 1: all A0/B0/B1 reads, t+1 stages (nbuf), 32 MFMA
        RD_AH(0); RD_BH(0, b0_); RD_BH(1, b1_);
        GLD_B(1, nbuf, k1);
        GLD_A(1, nbuf, k1);
        MFMA16(0, 0, b0_);
        MFMA16(0, 1, b1_);
        RD_AH(1);
        // mid barrier: every wave's cbuf A0/B0 reads are consumed by now
        __builtin_amdgcn_s_barrier();
        __builtin_amdgcn_sched_barrier(0);
        // region 2: t+2 stages (cbuf, now safe), 32 MFMA on A1
        if (kt < 14) { GLD_A(0, cbuf, k2); GLD_B(0, cbuf, k2); }
        MFMA16(1, 0, b0_);
        MFMA16(1, 1, b1_);
    }
    // peel kt = 15 (buf 1, no staging)
    {
        int cbuf = 1;
        asm volatile("s_waitcnt vmcnt(0)" ::: "memory");
        __builtin_amdgcn_s_barrier();
        __builtin_amdgcn_sched_barrier(0);
        RD_AH(0); RD_BH(0, b0_); RD_BH(1, b1_);
        MFMA16(0, 0, b0_);
        MFMA16(0, 1, b1_);
        RD_AH(1);
        MFMA16(1, 0, b0_);
        MFMA16(1, 1, b1_);
    }
#undef GLD_A
#undef GLD_B
#undef RD_AH
#undef RD_BH
#undef MFMA16

    // epilogue: GLU activation + residual in-place (r8-proven form)
    #pragma unroll
    for (int i = 0; i < 8; ++i) {
        #pragma unroll
        for (int pb = 0; pb < 2; ++pb) {
            int col = p0g + (wc * 2 + pb) * 16 + (lane & 15);
            float b1v = bg[col];
            float b2v = bg[1024 + col];
            #pragma unroll
            for (int r = 0; r < 4; ++r) {
                int m = m0 + wr * 128 + i * 16 + (lane >> 4) * 4 + r;
                size_t idx = (size_t)m * 1024 + col;
                float g1 = acc[i][pb * 2][r] + b1v;
                float g2 = acc[i][pb * 2 + 1][r] + b2v;
                hb[idx] = f2bf(bf2f(hb[idx]) + g1 * sigmoidf(g2));
            }
        }
    }
}

// ---------------- K5: decoder GEMM + in-loop LN stats + fold ---------------
__global__ __launch_bounds__(256) void k_dec_mfma(
        const u16* __restrict__ hb, const u16* __restrict__ WdT,
        const float* __restrict__ c12, float* __restrict__ out) {
    __shared__ __align__(16) char smem[66560];
    u16* As = (u16*)smem;
    u16* Bs = (u16*)(smem + 32768);
    float* Ts = (float*)smem;
    float* muL = (float*)(smem + 65536);
    float* rsL = (float*)(smem + 65536 + 512);
    int t = threadIdx.x;
    int lane = t & 63, wid = t >> 6;
    int wr = wid & 1, wc = wid >> 1;
    int m0 = blockIdx.x * 128;
    int bb = m0 >> 10, l0 = m0 & 1023;

    int gsrc = (((lane & 7) ^ (lane >> 3)) * 8);
    int rr4[4];
    #pragma unroll
    for (int c = 0; c < 4; ++c) rr4[c] = (wid * 4 + c) * 8 + (lane >> 3);
    int co[2];
    co[0] = (((lane >> 4) + 0) ^ (lane & 7)) * 8;
    co[1] = (((lane >> 4) + 4) ^ (lane & 7)) * 8;
    int arow[4], brow[4];
    #pragma unroll
    for (int i = 0; i < 4; ++i) arow[i] = (wr * 64 + i * 16 + (lane & 15)) * 64;
    #pragma unroll
    for (int q = 0; q < 4; ++q) brow[q] = (wc * 64 + q * 16 + (lane & 15)) * 64;

    f32x4 acc[4][4] = {};
    float s1[4] = {}, s2[4] = {};
    #pragma unroll
    for (int c = 0; c < 4; ++c) {
        int ch = wid * 4 + c;
        gld16(&hb[(size_t)(m0 + rr4[c]) * 1024 + gsrc], &As[0 * 8192 + ch * 512]);
        gld16(&WdT[(size_t)rr4[c] * 1024 + gsrc], &Bs[0 * 8192 + ch * 512]);
    }
    __syncthreads();
    int cur = 0;
    for (int kt = 0; kt < 16; ++kt) {
        if (kt < 15) {
            int k0 = (kt + 1) * 64;
            #pragma unroll
            for (int c = 0; c < 4; ++c) {
                int ch = wid * 4 + c;
                gld16(&hb[(size_t)(m0 + rr4[c]) * 1024 + k0 + gsrc], &As[(cur ^ 1) * 8192 + ch * 512]);
                gld16(&WdT[(size_t)rr4[c] * 1024 + k0 + gsrc], &Bs[(cur ^ 1) * 8192 + ch * 512]);
            }
        }
        #pragma unroll
        for (int kh = 0; kh < 2; ++kh) {
            bf16x8 af[4], bfr[4];
            #pragma unroll
            for (int i = 0; i < 4; ++i) af[i] = *(const bf16x8*)&As[cur * 8192 + arow[i] + co[kh]];
            #pragma unroll
            for (int q = 0; q < 4; ++q) bfr[q] = *(const bf16x8*)&Bs[cur * 8192 + brow[q] + co[kh]];
            if (wid < 2) {
                #pragma unroll
                for (int i = 0; i < 4; ++i) {
                    short8 sa = *(short8*)&af[i];
                    #pragma unroll
                    for (int e = 0; e < 8; ++e) {
                        float v = bf2f((u16)sa[e]);
                        s1[i] += v;
                        s2[i] = fmaf(v, v, s2[i]);
                    }
                }
            }
            __builtin_amdgcn_s_setprio(1);
            #pragma unroll
            for (int i = 0; i < 4; ++i)
                #pragma unroll
                for (int q = 0; q < 4; ++q)
                    acc[i][q] = __builtin_amdgcn_mfma_f32_16x16x32_bf16(af[i], bfr[q], acc[i][q], 0, 0, 0);
            __builtin_amdgcn_s_setprio(0);
        }
        __syncthreads();
        cur ^= 1;
    }
    if (wid < 2) {
        #pragma unroll
        for (int i = 0; i < 4; ++i) {
            s1[i] += __shfl_xor(s1[i], 16);
            s2[i] += __shfl_xor(s2[i], 16);
            s1[i] += __shfl_xor(s1[i], 32);
            s2[i] += __shfl_xor(s2[i], 32);
            if (lane < 16) {
                int ml = wr * 64 + i * 16 + lane;
                float mu = s1[i] * (1.0f / 1024.0f);
                float var = s2[i] * (1.0f / 1024.0f) - mu * mu;
                muL[ml] = mu;
                rsL[ml] = rsqrtf(var + 1e-5f);
            }
        }
    }
    __syncthreads();
    #pragma unroll
    for (int ro = 0; ro < 2; ++ro) {
        if (wc == ro) {
            #pragma unroll
            for (int i = 0; i < 4; ++i)
                #pragma unroll
                for (int q = 0; q < 4; ++q) {
                    int sl = q * 16 + (lane & 15);
                    float c1v = c12[ro * 64 + sl];
                    float c2v = c12[128 + ro * 64 + sl];
                    #pragma unroll
                    for (int r = 0; r < 4; ++r) {
                        int ml = wr * 64 + i * 16 + (lane >> 4) * 4 + r;
                        float rst = rsL[ml];
                        Ts[sl * 132 + ml] = rst * acc[i][q][r] - muL[ml] * rst * c1v + c2v;
                    }
                }
        }
        __syncthreads();
        #pragma unroll
        for (int p = 0; p < 8; ++p) {
            int fid = p * 256 + t;
            int sl = fid >> 5, c = (fid & 31) * 4;
            float4 v = *(const float4*)&Ts[sl * 132 + c];
            *(float4*)&out[(size_t)bb * 131072 + (size_t)(ro * 64 + sl) * 1024 + l0 + c] = v;
        }
        __syncthreads();
    }
}

extern "C" void kernel_launch(void* const* d_in, const int* in_sizes, int n_in,
                              void* d_out, int out_size, void* d_ws, size_t ws_size,
                              hipStream_t stream) {
    (void)in_sizes; (void)n_in; (void)out_size; (void)ws_size;
    const float* x   = (const float*)d_in[0];
    const float* We  = (const float*)d_in[1];
    const float* be  = (const float*)d_in[2];
    const float* ldt = (const float*)d_in[3];
    const float* Alr = (const float*)d_in[4];
    const float* Aim = (const float*)d_in[5];
    const float* Cr  = (const float*)d_in[6];
    const float* Ci  = (const float*)d_in[7];
    const float* Dv  = (const float*)d_in[8];
    const float* Wg  = (const float*)d_in[9];
    const float* bg  = (const float*)d_in[10];
    const float* gam = (const float*)d_in[11];
    const float* bet = (const float*)d_in[12];
    const float* Wd  = (const float*)d_in[13];
    const float* bd  = (const float*)d_in[14];
    float* out = (float*)d_out;

    u16* hb = (u16*)d_ws;                       // 64 MiB
    u16* yg = hb + 33554432ull;                 // 64 MiB
    float* Kt = (float*)(yg + 33554432ull);     // 256 KB
    u16* WgT = (u16*)(Kt + 65536);              // 4 MiB
    u16* WdT = WgT + 2097152ull;                // 256 KB (gamma-scaled WdT)
    u16* WeT = WdT + 131072ull;                 // 256 KB (c12 alias after enc)
    u16* xb  = yg;                              // alias: xb dead before conv writes yg
    float* c12  = (float*)WeT;                  // alias: WeT dead after enc

    k_tcast<<<dim3(32, 16, 1), 256, 0, stream>>>(Wg, WgT, 1024, 2048, nullptr);
    k_tcast<<<dim3(2, 16, 1), 256, 0, stream>>>(Wd, WdT, 1024, 128, gam);
    k_tcast<<<dim3(16, 2, 1), 256, 0, stream>>>(We, WeT, 128, 1024, nullptr);
    k_tcast<<<dim3(16, 2, 32), 256, 0, stream>>>(x, xb, 128, 1024, nullptr);
    k_ssmk<<<256, 256, 0, stream>>>(ldt, Alr, Aim, Cr, Ci, Kt);
    k_enc_mfma<<<2048, 256, 0, stream>>>(xb, WeT, be, hb);
    k_conv<<<dim3(16, 32), 256, 0, stream>>>(hb, Kt, Dv, yg);
    k_c12<<<128, 256, 0, stream>>>(Wd, gam, bet, bd, c12);
    k_glu256<<<1024, 512, 0, stream>>>(yg, WgT, bg, hb);
    k_dec_mfma<<<256, 256, 0, stream>>>(hb, WdT, c12, out);
}

// Round 12
// 321.914 us; speedup vs baseline: 1.0324x; 1.0324x over previous
//
#include <hip/hip_runtime.h>
#include <hip/hip_bf16.h>
#include <math.h>

#define B_ 32
#define S_ 128
#define L_ 1024
#define D_ 1024

typedef unsigned short u16;
typedef __attribute__((ext_vector_type(8))) __bf16 bf16x8;
typedef __attribute__((ext_vector_type(8))) short short8;
typedef __attribute__((ext_vector_type(4))) float f32x4;

__device__ __forceinline__ float bf2f(u16 u) {
    return __uint_as_float(((unsigned)u) << 16);
}
__device__ __forceinline__ u16 f2bf(float f) {
    unsigned u = __float_as_uint(f);
    u += 0x7FFF + ((u >> 16) & 1);
    return (u16)(u >> 16);
}
__device__ __forceinline__ float gelu_tanh(float x) {
    float x3 = x * x * x;
    float t = tanhf(0.7978845608028654f * (x + 0.044715f * x3));
    return 0.5f * x * (1.0f + t);
}
__device__ __forceinline__ float sigmoidf(float x) {
    return 1.0f / (1.0f + expf(-x));
}
__device__ __forceinline__ void gld16(const void* g, void* l) {
    __builtin_amdgcn_global_load_lds((const __attribute__((address_space(1))) void*)g,
                                     (__attribute__((address_space(3))) void*)l, 16, 0, 0);
}

// ---------------- prep: all weight tcasts + ssmk + c12 in one launch -------
__device__ __forceinline__ void tcast_body(
        const float* __restrict__ src, u16* __restrict__ dst, int R, int C,
        const float* __restrict__ rowscale, int bx, int by, int t,
        float (*tile)[65]) {
    int c0 = bx * 64, r0 = by * 64;
    #pragma unroll
    for (int p = 0; p < 4; ++p) {
        int fid = p * 256 + t;
        int rr = fid >> 4, cc = (fid & 15) * 4;
        float4 v = *(const float4*)&src[(size_t)(r0 + rr) * C + c0 + cc];
        float sc = rowscale ? rowscale[r0 + rr] : 1.0f;
        tile[rr][cc + 0] = v.x * sc; tile[rr][cc + 1] = v.y * sc;
        tile[rr][cc + 2] = v.z * sc; tile[rr][cc + 3] = v.w * sc;
    }
    __syncthreads();
    #pragma unroll
    for (int p = 0; p < 4; ++p) {
        int fid = p * 256 + t;
        int rr = fid >> 4, cc = (fid & 15) * 4;
        ushort4 o;
        o.x = f2bf(tile[cc + 0][rr]);
        o.y = f2bf(tile[cc + 1][rr]);
        o.z = f2bf(tile[cc + 2][rr]);
        o.w = f2bf(tile[cc + 3][rr]);
        *(ushort4*)&dst[(size_t)(c0 + rr) * R + r0 + cc] = o;
    }
}

__global__ __launch_bounds__(256) void k_prep(
        const float* __restrict__ Wg, u16* __restrict__ WgT,
        const float* __restrict__ Wd, const float* __restrict__ gam,
        u16* __restrict__ WdT,
        const float* __restrict__ We, u16* __restrict__ WeT,
        const float* __restrict__ x, u16* __restrict__ xb,
        const float* __restrict__ ldt, const float* __restrict__ Alr,
        const float* __restrict__ Aim, const float* __restrict__ Cr,
        const float* __restrict__ Ci, float* __restrict__ Kt,
        const float* __restrict__ bet, const float* __restrict__ bd,
        float* __restrict__ c12) {
    __shared__ float tile[64][65];
    __shared__ float r1[4], r2[4];
    int blk = blockIdx.x;
    int t = threadIdx.x;
    if (blk < 512) {
        // Wg: f32 [1024][2048] -> bf16 [2048][1024]
        tcast_body(Wg, WgT, 1024, 2048, nullptr, blk & 31, blk >> 5, t, tile);
    } else if (blk < 544) {
        // Wd (gamma-scaled rows): f32 [1024][128] -> bf16 [128][1024]
        int id = blk - 512;
        tcast_body(Wd, WdT, 1024, 128, gam, id & 1, id >> 1, t, tile);
    } else if (blk < 576) {
        // We: f32 [128][1024] -> bf16 [1024][128]
        int id = blk - 544;
        tcast_body(We, WeT, 128, 1024, nullptr, id & 15, id >> 4, t, tile);
    } else if (blk < 1600) {
        // x: per-batch f32 [128][1024] -> bf16 [1024][128]
        int id = blk - 576;
        int bz = id >> 5;
        tcast_body(x + (size_t)bz * 131072, xb + (size_t)bz * 131072,
                   128, 1024, nullptr, id & 15, (id >> 4) & 1, t, tile);
    } else if (blk < 1856) {
        // S4D SSM kernel -> Kt[j][d]
        int tid = (blk - 1600) * 256 + t;
        int d = tid & (D_ - 1);
        int j = tid >> 10;
        float dt = expf(ldt[d]);
        float acc = 0.f;
        #pragma unroll
        for (int n = 0; n < 4; ++n) {
            float ar = -expf(Alr[d * 4 + n]);
            float ai = Aim[d * 4 + n];
            float wr = ar * dt, wi = ai * dt;
            float ew = expf(wr);
            float sw, cw; sincosf(wi, &sw, &cw);
            float ur = ew * cw - 1.0f, ui = ew * sw;
            float inv = 1.0f / (ar * ar + ai * ai);
            float bdr = (ur * ar + ui * ai) * inv;
            float bdi = (ui * ar - ur * ai) * inv;
            float cr = Cr[d * 4 + n], ci = Ci[d * 4 + n];
            float cbr = cr * bdr - ci * bdi;
            float cbi = cr * bdi + ci * bdr;
            float ej = expf(wr * (float)j);
            float sj, cj; sincosf(wi * (float)j, &sj, &cj);
            acc += 2.0f * ej * (cbr * cj - cbi * sj);
        }
        Kt[j * D_ + d] = acc;
    } else {
        // c12: c1[s]=sum gam_k Wd[k,s]; c2[s]=sum bet_k Wd[k,s]+bd[s]
        int s = blk - 1856;
        float a1 = 0.f, a2 = 0.f;
        #pragma unroll
        for (int it = 0; it < 4; ++it) {
            int k = it * 256 + t;
            float w = Wd[(size_t)k * 128 + s];
            a1 += gam[k] * w;
            a2 += bet[k] * w;
        }
        #pragma unroll
        for (int off = 32; off > 0; off >>= 1) {
            a1 += __shfl_down(a1, off);
            a2 += __shfl_down(a2, off);
        }
        int wid = t >> 6, lane = t & 63;
        if (lane == 0) { r1[wid] = a1; r2[wid] = a2; }
        __syncthreads();
        if (t == 0) {
            c12[s] = r1[0] + r1[1] + r1[2] + r1[3];
            c12[128 + s] = r2[0] + r2[1] + r2[2] + r2[3] + bd[s];
        }
    }
}

// ---------------- K1: encoder MFMA ------------------------------------------
__global__ __launch_bounds__(256) void k_enc_mfma(
        const u16* __restrict__ xb, const u16* __restrict__ WeT,
        const float* __restrict__ be, u16* __restrict__ hb) {
    __shared__ u16 As[128 * 128];
    __shared__ u16 Bs[128 * 128];
    int t = threadIdx.x;
    int lane = t & 63, wid = t >> 6;
    int wr = wid & 1, wc = wid >> 1;
    int orig = blockIdx.x;
    int wgid = (orig & 7) * 256 + (orig >> 3);
    int m0 = (wgid >> 3) * 128;
    int e0 = (wgid & 7) * 128;

    #pragma unroll
    for (int c = 0; c < 8; ++c) {
        int ch = wid * 8 + c;
        int r = ch * 4 + (lane >> 4);
        int g = (lane & 15) ^ (r & 15);
        gld16(&xb[(size_t)(m0 + r) * 128 + g * 8], &As[ch * 512]);
        gld16(&WeT[(size_t)(e0 + r) * 128 + g * 8], &Bs[ch * 512]);
    }
    int co4[4];
    #pragma unroll
    for (int kh = 0; kh < 4; ++kh)
        co4[kh] = ((((lane >> 4) + kh * 4) ^ (lane & 15)) * 8);
    int arow[4], brow[4];
    #pragma unroll
    for (int i = 0; i < 4; ++i) arow[i] = (wr * 64 + i * 16 + (lane & 15)) * 128;
    #pragma unroll
    for (int q = 0; q < 4; ++q) brow[q] = (wc * 64 + q * 16 + (lane & 15)) * 128;

    __syncthreads();
    f32x4 acc[4][4] = {};
    #pragma unroll
    for (int kh = 0; kh < 4; ++kh) {
        bf16x8 af[4], bfr[4];
        #pragma unroll
        for (int i = 0; i < 4; ++i) af[i] = *(const bf16x8*)&As[arow[i] + co4[kh]];
        #pragma unroll
        for (int q = 0; q < 4; ++q) bfr[q] = *(const bf16x8*)&Bs[brow[q] + co4[kh]];
        __builtin_amdgcn_s_setprio(1);
        #pragma unroll
        for (int i = 0; i < 4; ++i)
            #pragma unroll
            for (int q = 0; q < 4; ++q)
                acc[i][q] = __builtin_amdgcn_mfma_f32_16x16x32_bf16(af[i], bfr[q], acc[i][q], 0, 0, 0);
        __builtin_amdgcn_s_setprio(0);
    }
    #pragma unroll
    for (int q = 0; q < 4; ++q) {
        int e = e0 + wc * 64 + q * 16 + (lane & 15);
        float bias = be[e];
        #pragma unroll
        for (int i = 0; i < 4; ++i) {
            #pragma unroll
            for (int r = 0; r < 4; ++r) {
                int m = m0 + wr * 64 + i * 16 + (lane >> 4) * 4 + r;
                hb[(size_t)m * 1024 + e] = f2bf(acc[i][q][r] + bias);
            }
        }
    }
}

// ---------------- K2: conv, halo-free ring sweep ---------------------------
__global__ __launch_bounds__(256) void k_conv(
        const u16* __restrict__ hb, const float* __restrict__ Kt,
        const float* __restrict__ Dv, u16* __restrict__ yg) {
    __shared__ float hs[128][68];
    int b = blockIdx.y;
    int d0 = blockIdx.x * 64;
    int t = threadIdx.x;
    int dl = t & 63, lg = t >> 6;
    {
        int r = 64 + (t >> 2), cg0 = (t & 3) * 16;
        #pragma unroll
        for (int j = 0; j < 4; ++j)
            *(float4*)&hs[r][cg0 + j * 4] = make_float4(0.f, 0.f, 0.f, 0.f);
    }
    float kr[64];
    #pragma unroll
    for (int j = 0; j < 64; ++j) kr[j] = Kt[j * 1024 + d0 + dl];
    float Dd = Dv[d0 + dl];
    int lr = t >> 2, cg = (t & 3) * 16;
    for (int it = 0; it < 16; ++it) {
        int l0 = it * 64;
        {
            int l = l0 + lr;
            int row = l & 127;
            const u16* src = &hb[((size_t)b * 1024 + l) * 1024 + d0 + cg];
            #pragma unroll
            for (int h = 0; h < 2; ++h) {
                ushort4 u0 = *(const ushort4*)&src[h * 8];
                ushort4 u1 = *(const ushort4*)&src[h * 8 + 4];
                *(float4*)&hs[row][cg + h * 8] =
                    make_float4(bf2f(u0.x), bf2f(u0.y), bf2f(u0.z), bf2f(u0.w));
                *(float4*)&hs[row][cg + h * 8 + 4] =
                    make_float4(bf2f(u1.x), bf2f(u1.y), bf2f(u1.z), bf2f(u1.w));
            }
        }
        __syncthreads();
        float acc[16] = {};
        int rb = l0 + 65 + lg * 16;
        #pragma unroll
        for (int s = 0; s < 15; ++s) {
            float hv = hs[(rb + s) & 127][dl];
            #pragma unroll
            for (int i = 0; i <= 14; ++i)
                if (i <= s) acc[i] = fmaf(kr[i + 63 - s], hv, acc[i]);
        }
        #pragma unroll
        for (int s = 15; s < 64; ++s) {
            float hv = hs[(rb + s) & 127][dl];
            #pragma unroll
            for (int i = 0; i < 16; ++i)
                acc[i] = fmaf(kr[i + 63 - s], hv, acc[i]);
        }
        #pragma unroll
        for (int s = 64; s < 79; ++s) {
            float hv = hs[(rb + s) & 127][dl];
            #pragma unroll
            for (int i = 1; i < 16; ++i)
                if (i >= s - 63) acc[i] = fmaf(kr[i + 63 - s], hv, acc[i]);
        }
        #pragma unroll
        for (int i = 0; i < 16; ++i) {
            int l = l0 + lg * 16 + i;
            float z = hs[l & 127][dl];
            float y = acc[i] + Dd * z;
            yg[((size_t)b * 1024 + l) * 1024 + d0 + dl] = f2bf(gelu_tanh(y));
        }
        __syncthreads();
    }
}

// ---------------- K3: GLU GEMM 256x256 (r11-proven, frozen) ----------------
__global__ __launch_bounds__(512, 2) void k_glu256(
        const u16* __restrict__ yg, const u16* __restrict__ WgT,
        const float* __restrict__ bg, u16* __restrict__ hb) {
    __shared__ u16 S[65536];
    int t = threadIdx.x;
    int lane = t & 63, wid = t >> 6;
    int wr = wid >> 2, wc = wid & 3;

    int orig = blockIdx.x;
    int wgid = (orig & 7) * 128 + (orig >> 3);
    int m0 = (wgid >> 3) * 256;
    int p0g = (wgid & 7) * 128;

    int gofs = (((lane & 7) ^ ((lane >> 3) & 7)) * 8);
    int ch0 = wid * 2, ch1 = ch0 + 1;
    int dst0 = ch0 * 512 + lane * 8;
    int dst1 = ch1 * 512 + lane * 8;
    int gmA[2][2], gmB[2][2];
    #pragma unroll
    for (int h = 0; h < 2; ++h) {
        #pragma unroll
        for (int j = 0; j < 2; ++j) {
            int ch = ch0 + j;
            gmA[h][j] = m0 + (ch >> 3) * 128 + h * 64 + (ch & 7) * 8 + (lane >> 3);
            int r = (ch >> 2) * 64 + h * 32 + (ch & 3) * 8 + (lane >> 3);
            gmB[h][j] = ((r >> 4) & 1) * 1024 + p0g + (((r >> 5) << 4) | (r & 15));
        }
    }
    int co[2];
    co[0] = (((lane >> 4) + 0) ^ (lane & 7)) * 8;
    co[1] = (((lane >> 4) + 4) ^ (lane & 7)) * 8;
    int arow[4], brow[2];
    #pragma unroll
    for (int i = 0; i < 4; ++i) arow[i] = (wr * 64 + i * 16 + (lane & 15)) * 64;
    #pragma unroll
    for (int q = 0; q < 2; ++q) brow[q] = (wc * 32 + q * 16 + (lane & 15)) * 64;

#define GLD_A(H, BUF, K0) { u16* d_ = &S[((BUF) * 2 + (H)) * 8192]; \
    gld16(&yg[(size_t)gmA[H][0] * 1024 + (K0) + gofs], d_ + dst0); \
    gld16(&yg[(size_t)gmA[H][1] * 1024 + (K0) + gofs], d_ + dst1); }
#define GLD_B(H, BUF, K0) { u16* d_ = &S[32768 + ((BUF) * 2 + (H)) * 8192]; \
    gld16(&WgT[(size_t)gmB[H][0] * 1024 + (K0) + gofs], d_ + dst0); \
    gld16(&WgT[(size_t)gmB[H][1] * 1024 + (K0) + gofs], d_ + dst1); }

#define RD_AH(MS) { const u16* Ar_ = &S[(cbuf * 2 + (MS)) * 8192]; \
    _Pragma("unroll") for (int i = 0; i < 4; ++i) { \
        a_[i][0] = *(const bf16x8*)&Ar_[arow[i] + co[0]]; \
        a_[i][1] = *(const bf16x8*)&Ar_[arow[i] + co[1]]; } }
#define RD_BH(NS, BB) { const u16* Br_ = &S[32768 + (cbuf * 2 + (NS)) * 8192]; \
    _Pragma("unroll") for (int q = 0; q < 2; ++q) { \
        BB[q][0] = *(const bf16x8*)&Br_[brow[q] + co[0]]; \
        BB[q][1] = *(const bf16x8*)&Br_[brow[q] + co[1]]; } }
#define MFMA16(MS, NS, BB) { __builtin_amdgcn_s_setprio(1); \
    _Pragma("unroll") for (int i = 0; i < 4; ++i) \
        _Pragma("unroll") for (int q = 0; q < 2; ++q) { \
            acc[(MS) * 4 + i][(NS) * 2 + q] = __builtin_amdgcn_mfma_f32_16x16x32_bf16( \
                a_[i][0], BB[q][0], acc[(MS) * 4 + i][(NS) * 2 + q], 0, 0, 0); \
            acc[(MS) * 4 + i][(NS) * 2 + q] = __builtin_amdgcn_mfma_f32_16x16x32_bf16( \
                a_[i][1], BB[q][1], acc[(MS) * 4 + i][(NS) * 2 + q], 0, 0, 0); } \
    __builtin_amdgcn_s_setprio(0); }

    f32x4 acc[8][4] = {};
    bf16x8 a_[4][2], b0_[2][2], b1_[2][2];

    GLD_A(0, 0, 0); GLD_B(0, 0, 0); GLD_B(1, 0, 0); GLD_A(1, 0, 0);
    GLD_A(0, 1, 64); GLD_B(0, 1, 64);

    for (int kt = 0; kt < 15; ++kt) {
        int cbuf = kt & 1, nbuf = cbuf ^ 1;
        int k1 = (kt + 1) * 64, k2 = (kt + 2) * 64;
        asm volatile("s_waitcnt vmcnt(4)" ::: "memory");
        __builtin_amdgcn_s_barrier();
        __builtin_amdgcn_sched_barrier(0);
        RD_AH(0); RD_BH(0, b0_); RD_BH(1, b1_);
        GLD_B(1, nbuf, k1);
        GLD_A(1, nbuf, k1);
        MFMA16(0, 0, b0_);
        MFMA16(0, 1, b1_);
        RD_AH(1);
        __builtin_amdgcn_s_barrier();
        __builtin_amdgcn_sched_barrier(0);
        if (kt < 14) { GLD_A(0, cbuf, k2); GLD_B(0, cbuf, k2); }
        MFMA16(1, 0, b0_);
        MFMA16(1, 1, b1_);
    }
    {
        int cbuf = 1;
        asm volatile("s_waitcnt vmcnt(0)" ::: "memory");
        __builtin_amdgcn_s_barrier();
        __builtin_amdgcn_sched_barrier(0);
        RD_AH(0); RD_BH(0, b0_); RD_BH(1, b1_);
        MFMA16(0, 0, b0_);
        MFMA16(0, 1, b1_);
        RD_AH(1);
        MFMA16(1, 0, b0_);
        MFMA16(1, 1, b1_);
    }
#undef GLD_A
#undef GLD_B
#undef RD_AH
#undef RD_BH
#undef MFMA16

    #pragma unroll
    for (int i = 0; i < 8; ++i) {
        #pragma unroll
        for (int pb = 0; pb < 2; ++pb) {
            int col = p0g + (wc * 2 + pb) * 16 + (lane & 15);
            float b1v = bg[col];
            float b2v = bg[1024 + col];
            #pragma unroll
            for (int r = 0; r < 4; ++r) {
                int m = m0 + wr * 128 + i * 16 + (lane >> 4) * 4 + r;
                size_t idx = (size_t)m * 1024 + col;
                float g1 = acc[i][pb * 2][r] + b1v;
                float g2 = acc[i][pb * 2 + 1][r] + b2v;
                hb[idx] = f2bf(bf2f(hb[idx]) + g1 * sigmoidf(g2));
            }
        }
    }
}

// ---------------- K5: decoder GEMM + in-loop LN stats + fold ---------------
__global__ __launch_bounds__(256) void k_dec_mfma(
        const u16* __restrict__ hb, const u16* __restrict__ WdT,
        const float* __restrict__ c12, float* __restrict__ out) {
    __shared__ __align__(16) char smem[66560];
    u16* As = (u16*)smem;
    u16* Bs = (u16*)(smem + 32768);
    float* Ts = (float*)smem;
    float* muL = (float*)(smem + 65536);
    float* rsL = (float*)(smem + 65536 + 512);
    int t = threadIdx.x;
    int lane = t & 63, wid = t >> 6;
    int wr = wid & 1, wc = wid >> 1;
    int m0 = blockIdx.x * 128;
    int bb = m0 >> 10, l0 = m0 & 1023;

    int gsrc = (((lane & 7) ^ (lane >> 3)) * 8);
    int rr4[4];
    #pragma unroll
    for (int c = 0; c < 4; ++c) rr4[c] = (wid * 4 + c) * 8 + (lane >> 3);
    int co[2];
    co[0] = (((lane >> 4) + 0) ^ (lane & 7)) * 8;
    co[1] = (((lane >> 4) + 4) ^ (lane & 7)) * 8;
    int arow[4], brow[4];
    #pragma unroll
    for (int i = 0; i < 4; ++i) arow[i] = (wr * 64 + i * 16 + (lane & 15)) * 64;
    #pragma unroll
    for (int q = 0; q < 4; ++q) brow[q] = (wc * 64 + q * 16 + (lane & 15)) * 64;

    f32x4 acc[4][4] = {};
    float s1[4] = {}, s2[4] = {};
    #pragma unroll
    for (int c = 0; c < 4; ++c) {
        int ch = wid * 4 + c;
        gld16(&hb[(size_t)(m0 + rr4[c]) * 1024 + gsrc], &As[0 * 8192 + ch * 512]);
        gld16(&WdT[(size_t)rr4[c] * 1024 + gsrc], &Bs[0 * 8192 + ch * 512]);
    }
    __syncthreads();
    int cur = 0;
    for (int kt = 0; kt < 16; ++kt) {
        if (kt < 15) {
            int k0 = (kt + 1) * 64;
            #pragma unroll
            for (int c = 0; c < 4; ++c) {
                int ch = wid * 4 + c;
                gld16(&hb[(size_t)(m0 + rr4[c]) * 1024 + k0 + gsrc], &As[(cur ^ 1) * 8192 + ch * 512]);
                gld16(&WdT[(size_t)rr4[c] * 1024 + k0 + gsrc], &Bs[(cur ^ 1) * 8192 + ch * 512]);
            }
        }
        #pragma unroll
        for (int kh = 0; kh < 2; ++kh) {
            bf16x8 af[4], bfr[4];
            #pragma unroll
            for (int i = 0; i < 4; ++i) af[i] = *(const bf16x8*)&As[cur * 8192 + arow[i] + co[kh]];
            #pragma unroll
            for (int q = 0; q < 4; ++q) bfr[q] = *(const bf16x8*)&Bs[cur * 8192 + brow[q] + co[kh]];
            if (wid < 2) {
                #pragma unroll
                for (int i = 0; i < 4; ++i) {
                    short8 sa = *(short8*)&af[i];
                    #pragma unroll
                    for (int e = 0; e < 8; ++e) {
                        float v = bf2f((u16)sa[e]);
                        s1[i] += v;
                        s2[i] = fmaf(v, v, s2[i]);
                    }
                }
            }
            __builtin_amdgcn_s_setprio(1);
            #pragma unroll
            for (int i = 0; i < 4; ++i)
                #pragma unroll
                for (int q = 0; q < 4; ++q)
                    acc[i][q] = __builtin_amdgcn_mfma_f32_16x16x32_bf16(af[i], bfr[q], acc[i][q], 0, 0, 0);
            __builtin_amdgcn_s_setprio(0);
        }
        __syncthreads();
        cur ^= 1;
    }
    if (wid < 2) {
        #pragma unroll
        for (int i = 0; i < 4; ++i) {
            s1[i] += __shfl_xor(s1[i], 16);
            s2[i] += __shfl_xor(s2[i], 16);
            s1[i] += __shfl_xor(s1[i], 32);
            s2[i] += __shfl_xor(s2[i], 32);
            if (lane < 16) {
                int ml = wr * 64 + i * 16 + lane;
                float mu = s1[i] * (1.0f / 1024.0f);
                float var = s2[i] * (1.0f / 1024.0f) - mu * mu;
                muL[ml] = mu;
                rsL[ml] = rsqrtf(var + 1e-5f);
            }
        }
    }
    __syncthreads();
    #pragma unroll
    for (int ro = 0; ro < 2; ++ro) {
        if (wc == ro) {
            #pragma unroll
            for (int i = 0; i < 4; ++i)
                #pragma unroll
                for (int q = 0; q < 4; ++q) {
                    int sl = q * 16 + (lane & 15);
                    float c1v = c12[ro * 64 + sl];
                    float c2v = c12[128 + ro * 64 + sl];
                    #pragma unroll
                    for (int r = 0; r < 4; ++r) {
                        int ml = wr * 64 + i * 16 + (lane >> 4) * 4 + r;
                        float rst = rsL[ml];
                        Ts[sl * 132 + ml] = rst * acc[i][q][r] - muL[ml] * rst * c1v + c2v;
                    }
                }
        }
        __syncthreads();
        #pragma unroll
        for (int p = 0; p < 8; ++p) {
            int fid = p * 256 + t;
            int sl = fid >> 5, c = (fid & 31) * 4;
            float4 v = *(const float4*)&Ts[sl * 132 + c];
            *(float4*)&out[(size_t)bb * 131072 + (size_t)(ro * 64 + sl) * 1024 + l0 + c] = v;
        }
        __syncthreads();
    }
}

extern "C" void kernel_launch(void* const* d_in, const int* in_sizes, int n_in,
                              void* d_out, int out_size, void* d_ws, size_t ws_size,
                              hipStream_t stream) {
    (void)in_sizes; (void)n_in; (void)out_size; (void)ws_size;
    const float* x   = (const float*)d_in[0];
    const float* We  = (const float*)d_in[1];
    const float* be  = (const float*)d_in[2];
    const float* ldt = (const float*)d_in[3];
    const float* Alr = (const float*)d_in[4];
    const float* Aim = (const float*)d_in[5];
    const float* Cr  = (const float*)d_in[6];
    const float* Ci  = (const float*)d_in[7];
    const float* Dv  = (const float*)d_in[8];
    const float* Wg  = (const float*)d_in[9];
    const float* bg  = (const float*)d_in[10];
    const float* gam = (const float*)d_in[11];
    const float* bet = (const float*)d_in[12];
    const float* Wd  = (const float*)d_in[13];
    const float* bd  = (const float*)d_in[14];
    float* out = (float*)d_out;

    u16* hb = (u16*)d_ws;                       // 64 MiB
    u16* yg = hb + 33554432ull;                 // 64 MiB
    float* Kt = (float*)(yg + 33554432ull);     // 256 KB
    u16* WgT = (u16*)(Kt + 65536);              // 4 MiB
    u16* WdT = WgT + 2097152ull;                // 256 KB (gamma-scaled WdT)
    u16* WeT = WdT + 131072ull;                 // 256 KB
    float* c12 = (float*)(WeT + 131072ull);     // 1 KB (own slot; prep-safe)
    u16* xb  = yg;                              // alias: xb dead before conv writes yg

    k_prep<<<1984, 256, 0, stream>>>(Wg, WgT, Wd, gam, WdT, We, WeT, x, xb,
                                     ldt, Alr, Aim, Cr, Ci, Kt, bet, bd, c12);
    k_enc_mfma<<<2048, 256, 0, stream>>>(xb, WeT, be, hb);
    k_conv<<<dim3(16, 32), 256, 0, stream>>>(hb, Kt, Dv, yg);
    k_glu256<<<1024, 512, 0, stream>>>(yg, WgT, bg, hb);
    k_dec_mfma<<<256, 256, 0, stream>>>(hb, WdT, c12, out);
}